// Round 4
// baseline (1002.019 us; speedup 1.0000x reference)
//
#include <hip/hip_runtime.h>

#define B_ 2
#define S_ 2048
#define E_ 4096
#define H_ 32
#define KV_ 8
#define D_ 128

typedef __bf16 v8bf __attribute__((ext_vector_type(8)));
typedef __bf16 v4bf __attribute__((ext_vector_type(4)));
typedef float  v4f  __attribute__((ext_vector_type(4)));

static __device__ __forceinline__ v4f mfma16(v8bf a, v8bf b, v4f c) {
    return __builtin_amdgcn_mfma_f32_16x16x32_bf16(a, b, c, 0, 0, 0);
}

// async global->LDS, 16B per lane; LDS dest = wave-uniform base + lane*16
static __device__ __forceinline__ void load_lds16(const void* g, void* l) {
    __builtin_amdgcn_global_load_lds(
        (const __attribute__((address_space(1))) void*)g,
        (__attribute__((address_space(3))) void*)l, 16, 0, 0);
}

// ---------------- cast fp32 -> bf16 (vectorized) ----------------
__global__ __launch_bounds__(256) void cast_f32_to_bf16(
        const float4* __restrict__ in, v4bf* __restrict__ out, int n4) {
    int i = blockIdx.x * blockDim.x + threadIdx.x;
    if (i >= n4) return;
    float4 v = in[i];
    v4bf o;
    o[0] = (__bf16)v.x; o[1] = (__bf16)v.y; o[2] = (__bf16)v.z; o[3] = (__bf16)v.w;
    out[i] = o;
}

// ---------------- in-place RoPE on bf16 (B,S,nh*128) ----------------
__global__ __launch_bounds__(256) void rope_inplace(
        __bf16* __restrict__ qk, const int* __restrict__ pos, int nh, int rowstride) {
    int idx = blockIdx.x * blockDim.x + threadIdx.x;
    int d = idx & 63;
    int t = idx >> 6;
    int h = t % nh;
    int bs = t / nh;
    if (bs >= B_ * S_) return;
    int s = bs & (S_ - 1);
    float p = (float)pos[s];
    float inv = expf(-(float)d * (1.0f / 64.0f) * 13.122363377404329f);
    float ang = p * inv;
    float c = cosf(ang), sn = sinf(ang);
    size_t off = (size_t)bs * rowstride + (size_t)h * D_;
    float x1 = (float)qk[off + d];
    float x2 = (float)qk[off + d + 64];
    qk[off + d]      = (__bf16)(x1 * c - x2 * sn);
    qk[off + d + 64] = (__bf16)(x2 * c + x1 * sn);
}

// ---------------- GEMM 256x256/BK=64, 8 waves, phase-split -------------------
// Same verified structure as round 3, MINUS the per-phase sched_barrier(0)
// order-pins (m141: pinning defeats the scheduler). Memory ordering across
// tile boundaries is carried by the inline-asm vmcnt/lgkmcnt memory clobbers.
template <int EPI>
__global__ __launch_bounds__(512, 2) void gemm_bt(
        const __bf16* __restrict__ A, const __bf16* __restrict__ Bm,
        void* __restrict__ Cv, void* __restrict__ Cv2, int M, int N, int K) {
    __shared__ __bf16 As[2][256 * 64];
    __shared__ __bf16 Bs[2][256 * 64];
    const int tid  = threadIdx.x;
    const int wave = tid >> 6;
    const int lane = tid & 63;
    const int l15  = lane & 15;
    const int quad = lane >> 4;

    // XCD-chunked block swizzle (nwg % 8 == 0 for all our launches)
    const int nbx = N >> 8;
    const int nwg = (int)gridDim.x;
    const int swz = ((int)blockIdx.x & 7) * (nwg >> 3) + ((int)blockIdx.x >> 3);
    const int bm  = (swz / nbx) * 256;
    const int bn  = (swz % nbx) * 256;

    const int wr = wave >> 2;    // 0..1  (row group: 128 rows)
    const int wc = wave & 3;     // 0..3  (col group: 64 cols)

    v4f acc[8][4] = {};

    const int srow = wave * 8 + (lane >> 3);
    const int scc  = (lane & 7) ^ ((lane >> 3) & 7);

    auto stage = [&](int t, int buf) {
        const size_t k0 = (size_t)t * 64;
#pragma unroll
        for (int g = 0; g < 4; ++g) {
            load_lds16(A + (size_t)(bm + g * 64 + srow) * K + k0 + scc * 8,
                       (char*)&As[buf][0] + (size_t)g * 8192 + (size_t)wave * 1024);
            load_lds16(Bm + (size_t)(bn + g * 64 + srow) * K + k0 + scc * 8,
                       (char*)&Bs[buf][0] + (size_t)g * 8192 + (size_t)wave * 1024);
        }
    };

    stage(0, 0);   // prologue

    const int nt = K >> 6;
    for (int t = 0; t < nt; ++t) {
        const int cur = t & 1;
        if (t + 1 < nt) {
            stage(t + 1, cur ^ 1);
            asm volatile("s_waitcnt vmcnt(8)" ::: "memory");
        } else {
            asm volatile("s_waitcnt vmcnt(0)" ::: "memory");
        }
        __builtin_amdgcn_s_barrier();

        const __bf16* Asc = &As[cur][0];
        const __bf16* Bsc = &Bs[cur][0];
        v8bf a[4][2], b[2][2];

        auto rdA = [&](int mh) {
#pragma unroll
            for (int i = 0; i < 4; ++i)
#pragma unroll
                for (int kk = 0; kk < 2; ++kk)
                    a[i][kk] = *(const v8bf*)&Asc[
                        (wr * 128 + mh * 64 + i * 16 + l15) * 64 +
                        (((kk * 4 + quad) ^ (l15 & 7)) * 8)];
        };
        auto rdB = [&](int nh) {
#pragma unroll
            for (int j = 0; j < 2; ++j)
#pragma unroll
                for (int kk = 0; kk < 2; ++kk)
                    b[j][kk] = *(const v8bf*)&Bsc[
                        (wc * 64 + nh * 32 + j * 16 + l15) * 64 +
                        (((kk * 4 + quad) ^ (l15 & 7)) * 8)];
        };
        auto domfma = [&](int mh, int nh) {
            __builtin_amdgcn_s_setprio(1);
#pragma unroll
            for (int kk = 0; kk < 2; ++kk)
#pragma unroll
                for (int i = 0; i < 4; ++i)
#pragma unroll
                    for (int j = 0; j < 2; ++j)
                        acc[mh * 4 + i][nh * 2 + j] =
                            mfma16(a[i][kk], b[j][kk], acc[mh * 4 + i][nh * 2 + j]);
            __builtin_amdgcn_s_setprio(0);
        };

        // phase 0: (mh0, nh0)
        rdA(0); rdB(0);
        __builtin_amdgcn_s_barrier();
        domfma(0, 0);
        __builtin_amdgcn_s_barrier();
        // phase 1: (mh0, nh1) — reuse A
        rdB(1);
        __builtin_amdgcn_s_barrier();
        domfma(0, 1);
        __builtin_amdgcn_s_barrier();
        // phase 2: (mh1, nh1) — reuse B
        rdA(1);
        __builtin_amdgcn_s_barrier();
        domfma(1, 1);
        __builtin_amdgcn_s_barrier();
        // phase 3: (mh1, nh0)
        rdB(0);
        __builtin_amdgcn_s_barrier();
        domfma(1, 0);
        __builtin_amdgcn_s_barrier();
    }

    // epilogue: C/D layout col = lane&15, row = quad*4 + r (m89/m91 verified)
#pragma unroll
    for (int mi = 0; mi < 8; ++mi) {
#pragma unroll
        for (int nj = 0; nj < 4; ++nj) {
#pragma unroll
            for (int r = 0; r < 4; ++r) {
                int row = bm + wr * 128 + mi * 16 + quad * 4 + r;
                int col = bn + wc * 64 + nj * 16 + l15;
                float val = acc[mi][nj][r];
                if (EPI == 0) {
                    ((float*)Cv)[(size_t)row * N + col] = val;
                } else if (EPI == 1) {
                    ((__bf16*)Cv)[(size_t)row * N + col] = (__bf16)val;
                } else {
                    if (col < 1024) {
                        ((__bf16*)Cv)[(size_t)row * 1024 + col] = (__bf16)val;
                    } else {
                        int cc = col - 1024;
                        int b  = row >> 11, s = row & (S_ - 1);
                        int kv = cc >> 7,  d = cc & (D_ - 1);
                        ((__bf16*)Cv2)[((size_t)((b * KV_ + kv) * D_ + d)) * S_ + s] = (__bf16)val;
                    }
                }
            }
        }
    }
}

// ---------------- fused causal flash attention (8-wave, pipelined) ----------
// q: (B,S,E) bf16 roped; k: (B,S,KV*D) bf16 roped; vt: (B,KV,D,S) bf16
// Block = 8 waves = 128 queries of one (b,h); K/V^T 64-key tiles double-
// buffered in LDS (verified XOR chunk swizzles). Counted vmcnt(4) pipeline
// (4 DMAs/wave/tile). P tile per wave: [16][64] with chunk-XOR swizzle
// (stored chunk = logical ^ (row&7)) -> both the b16 writes and the b128
// A-fragment reads are ~2-way. LDS total = 80 KiB exactly -> 2 blocks/CU
// = 4 waves/SIMD (round-3 counters: 2 waves/SIMD was the latency wall).
__global__ __launch_bounds__(512, 4) void attn_fused(
        const __bf16* __restrict__ q, const __bf16* __restrict__ k,
        const __bf16* __restrict__ vt, __bf16* __restrict__ attn) {
    __shared__ __bf16 Ks[2][64 * 128];   // [key][d], chunk16 c at c^(key&15)
    __shared__ __bf16 Vs[2][128 * 64];   // [d][key], chunk16 c at c^(d&7)
    __shared__ __bf16 P[8][16 * 64];     // per-wave P, chunk8 c at c^(row&7)
    const int wave = threadIdx.x >> 6;
    const int lane = threadIdx.x & 63;

    // XCD-aware decode: 1024 blocks; each XCD owns bh in [xcd*8, xcd*8+8)
    // -> 2MB K/V working set per XCD L2 (verified: FETCH 79.6 -> 24.6 MB).
    const int wgid = blockIdx.x;
    const int xcd  = wgid & 7;
    const int slot = wgid >> 3;               // 0..127
    const int bh   = xcd * 8 + (slot >> 4);   // 8 bh per XCD
    const int qblk = 15 - (slot & 15);        // long blocks first (128-q blocks)
    const int b = bh >> 5;       // H=32
    const int h = bh & 31;
    const int kvh = h >> 2;      // rep = H/KV = 4
    const int q0 = qblk * 128 + wave * 16;
    const int l15  = lane & 15;
    const int quad = lane >> 4;

    const __bf16* qbase = q  + (size_t)(b * S_) * E_ + (size_t)h * D_;
    const __bf16* kbase = k  + (size_t)(b * S_) * (KV_ * D_) + (size_t)kvh * D_;
    const __bf16* vbase = vt + (size_t)((b * KV_ + kvh) * D_) * S_;
    __bf16* Pw = &P[wave][0];

    const int krow_l = lane >> 4;   // 0..3
    const int kcc    = lane & 15;
    const int vrow_l = lane >> 3;   // 0..7
    const int vcc    = lane & 7;

    auto stageK = [&](int t, int buf) {
#pragma unroll
        for (int i = 0; i < 2; ++i) {
            int g = wave * 2 + i;           // 0..15, 1KB each
            int row = g * 4 + krow_l;       // key 0..63
            int scc = kcc ^ (row & 15);
            load_lds16(kbase + (size_t)(t * 64 + row) * (KV_ * D_) + scc * 8,
                       (char*)&Ks[buf][0] + (size_t)g * 1024);
        }
    };
    auto stageV = [&](int t, int buf) {
#pragma unroll
        for (int i = 0; i < 2; ++i) {
            int g = wave * 2 + i;           // 0..15, 1KB each
            int row = g * 8 + vrow_l;       // d 0..127
            int scc = vcc ^ (row & 7);
            load_lds16(vbase + (size_t)row * S_ + t * 64 + scc * 8,
                       (char*)&Vs[buf][0] + (size_t)g * 1024);
        }
    };

    stageK(0, 0);
    stageV(0, 0);

    v8bf aq[4];
#pragma unroll
    for (int kc = 0; kc < 4; ++kc)
        aq[kc] = *(const v8bf*)(qbase + (size_t)(q0 + l15) * E_ + kc * 32 + quad * 8);

    v4f o[8] = {};
    float m_i[4], l_i[4];
#pragma unroll
    for (int r = 0; r < 4; ++r) { m_i[r] = -INFINITY; l_i[r] = 0.f; }

    const int ntiles = 2 * qblk + 2;           // block-uniform (covers 128 q)
    const int rowbase = q0 + quad * 4;
    const float scale = 0.08838834764831845f;

    for (int t = 0; t < ntiles; ++t) {
        const int cur = t & 1;
        if (t + 1 < ntiles) {
            stageK(t + 1, cur ^ 1);
            stageV(t + 1, cur ^ 1);
            asm volatile("s_waitcnt vmcnt(4)" ::: "memory");
        } else {
            asm volatile("s_waitcnt vmcnt(0)" ::: "memory");
        }
        __builtin_amdgcn_s_barrier();
        __builtin_amdgcn_sched_barrier(0);

        const int n0 = t * 64;
        const __bf16* Ksc = &Ks[cur][0];
        const __bf16* Vsc = &Vs[cur][0];

        // ---- QK^T: 16 queries x 64 keys, K from LDS ----
        v4f s[4] = {};
        __builtin_amdgcn_s_setprio(1);
#pragma unroll
        for (int kc = 0; kc < 4; ++kc) {
            v8bf kf[4];
#pragma unroll
            for (int j = 0; j < 4; ++j)
                kf[j] = *(const v8bf*)&Ksc[(j * 16 + l15) * 128 +
                                           (((kc * 4 + quad) ^ l15) * 8)];
#pragma unroll
            for (int j = 0; j < 4; ++j)
                s[j] = mfma16(aq[kc], kf[j], s[j]);
        }
        __builtin_amdgcn_s_setprio(0);

        // ---- scale + (boundary-only) causal mask ----
        float e[4][4];
        if (n0 + 63 > q0) {           // wave-uniform
#pragma unroll
            for (int j = 0; j < 4; ++j)
#pragma unroll
                for (int r = 0; r < 4; ++r) {
                    float v = s[j][r] * scale;
                    if (n0 + j * 16 + l15 > rowbase + r) v = -INFINITY;
                    e[j][r] = v;
                }
        } else {
#pragma unroll
            for (int j = 0; j < 4; ++j)
#pragma unroll
                for (int r = 0; r < 4; ++r)
                    e[j][r] = s[j][r] * scale;
        }

        // ---- online softmax ----
        float mloc[4];
#pragma unroll
        for (int r = 0; r < 4; ++r)
            mloc[r] = fmaxf(fmaxf(e[0][r], e[1][r]), fmaxf(e[2][r], e[3][r]));
#pragma unroll
        for (int off = 1; off < 16; off <<= 1)
#pragma unroll
            for (int r = 0; r < 4; ++r)
                mloc[r] = fmaxf(mloc[r], __shfl_xor(mloc[r], off, 64));

        float alpha[4], psum[4];
#pragma unroll
        for (int r = 0; r < 4; ++r) {
            float mnew = fmaxf(m_i[r], mloc[r]);
            alpha[r] = __expf(m_i[r] - mnew);
            m_i[r] = mnew;
#pragma unroll
            for (int j = 0; j < 4; ++j)
                e[j][r] = __expf(e[j][r] - mnew);
            psum[r] = (e[0][r] + e[1][r]) + (e[2][r] + e[3][r]);
        }
#pragma unroll
        for (int off = 1; off < 16; off <<= 1)
#pragma unroll
            for (int r = 0; r < 4; ++r)
                psum[r] += __shfl_xor(psum[r], off, 64);
#pragma unroll
        for (int r = 0; r < 4; ++r)
            l_i[r] = l_i[r] * alpha[r] + psum[r];
#pragma unroll
        for (int c = 0; c < 8; ++c)
#pragma unroll
            for (int r = 0; r < 4; ++r)
                o[c][r] *= alpha[r];

        // ---- P: C-layout -> wave-private LDS, chunk-XOR swizzled (ld 64) ----
        // element (row, col): stored chunk = (col>>3) ^ (row&7), keeps b16
        // writes ~2-way and makes b128 reads ~2-way (no pad needed).
#pragma unroll
        for (int j = 0; j < 4; ++j)
#pragma unroll
            for (int r = 0; r < 4; ++r) {
                int row = quad * 4 + r;
                int cl  = j * 2 + (l15 >> 3);
                Pw[row * 64 + (((cl ^ (row & 7)) << 3) | (l15 & 7))] = (__bf16)e[j][r];
            }

        // re-read as A-fragment: row l15, logical chunks quad / 4+quad
        v8bf ap0 = *(const v8bf*)&Pw[l15 * 64 + ((quad ^ (l15 & 7)) << 3)];
        v8bf ap1 = *(const v8bf*)&Pw[l15 * 64 + (((4 + quad) ^ (l15 & 7)) << 3)];

        // ---- PV: o[d-tile] += P * V^T, V from LDS ----
        __builtin_amdgcn_s_setprio(1);
#pragma unroll
        for (int c = 0; c < 8; ++c) {
            v8bf v0 = *(const v8bf*)&Vsc[(c * 16 + l15) * 64 +
                                         ((quad ^ (l15 & 7)) * 8)];
            v8bf v1 = *(const v8bf*)&Vsc[(c * 16 + l15) * 64 +
                                         (((4 + quad) ^ (l15 & 7)) * 8)];
            o[c] = mfma16(ap0, v0, o[c]);
            o[c] = mfma16(ap1, v1, o[c]);
        }
        __builtin_amdgcn_s_setprio(0);

        __builtin_amdgcn_sched_barrier(0);
        asm volatile("s_waitcnt lgkmcnt(0)" ::: "memory");
        __builtin_amdgcn_s_barrier();
        __builtin_amdgcn_sched_barrier(0);
    }

    float linv[4];
#pragma unroll
    for (int r = 0; r < 4; ++r) linv[r] = 1.0f / l_i[r];
    __bf16* obase = attn + (size_t)(b * S_) * E_ + (size_t)h * D_;
#pragma unroll
    for (int c = 0; c < 8; ++c)
#pragma unroll
        for (int r = 0; r < 4; ++r)
            obase[(size_t)(q0 + quad * 4 + r) * E_ + c * 16 + l15] =
                (__bf16)(o[c][r] * linv[r]);
}

extern "C" void kernel_launch(void* const* d_in, const int* in_sizes, int n_in,
                              void* d_out, int out_size, void* d_ws, size_t ws_size,
                              hipStream_t stream) {
    (void)in_sizes; (void)n_in; (void)out_size; (void)ws_size;
    const float* x  = (const float*)d_in[0];
    const float* wq = (const float*)d_in[1];
    const float* wk = (const float*)d_in[2];
    const float* wv = (const float*)d_in[3];
    const float* wo = (const float*)d_in[4];
    const int*   pos = (const int*)d_in[5];
    float* out = (float*)d_out;

    char* ws = (char*)d_ws;
    size_t off = 0;
    auto alloc = [&](size_t bytes) {
        char* p = ws + off;
        off += (bytes + 255) & ~(size_t)255;
        return p;
    };
    __bf16* xb   = (__bf16*)alloc((size_t)B_ * S_ * E_ * 2);
    __bf16* wqb  = (__bf16*)alloc((size_t)E_ * E_ * 2);
    __bf16* wkvb = (__bf16*)alloc((size_t)2 * KV_ * D_ * E_ * 2);  // [wk;wv] rows
    __bf16* wob  = (__bf16*)alloc((size_t)E_ * E_ * 2);
    __bf16* qb   = (__bf16*)alloc((size_t)B_ * S_ * E_ * 2);
    __bf16* kb   = (__bf16*)alloc((size_t)B_ * S_ * KV_ * D_ * 2);
    __bf16* vt   = (__bf16*)alloc((size_t)B_ * KV_ * D_ * S_ * 2);
    __bf16* at   = (__bf16*)alloc((size_t)B_ * S_ * E_ * 2);

    auto cast = [&](const float* in, __bf16* ob, size_t n) {
        int n4 = (int)(n / 4);
        cast_f32_to_bf16<<<(n4 + 255) / 256, 256, 0, stream>>>(
            (const float4*)in, (v4bf*)ob, n4);
    };
    cast(x,  xb,  (size_t)B_ * S_ * E_);
    cast(wq, wqb, (size_t)E_ * E_);
    cast(wk, wkvb, (size_t)KV_ * D_ * E_);
    cast(wv, wkvb + (size_t)KV_ * D_ * E_, (size_t)KV_ * D_ * E_);
    cast(wo, wob, (size_t)E_ * E_);

    const int M = B_ * S_;
    const int nwg_e = (E_ / 256) * (M / 256);            // 256
    const int nwg_kv = (2 * KV_ * D_ / 256) * (M / 256); // 128
    gemm_bt<1><<<dim3(nwg_e), 512, 0, stream>>>(
        xb, wqb, qb, nullptr, M, E_, E_);
    gemm_bt<2><<<dim3(nwg_kv), 512, 0, stream>>>(
        xb, wkvb, kb, vt, M, 2 * KV_ * D_, E_);

    rope_inplace<<<(B_ * S_ * H_ * 64 + 255) / 256, 256, 0, stream>>>(qb, pos, H_, E_);
    rope_inplace<<<(B_ * S_ * KV_ * 64 + 255) / 256, 256, 0, stream>>>(kb, pos, KV_, KV_ * D_);

    attn_fused<<<dim3(B_ * H_ * (S_ / 128)), 512, 0, stream>>>(qb, kb, vt, at);

    gemm_bt<0><<<dim3(nwg_e), 512, 0, stream>>>(
        at, wob, out, nullptr, M, E_, E_);
}

// Round 5
// 889.143 us; speedup vs baseline: 1.1269x; 1.1269x over previous
//
#include <hip/hip_runtime.h>

#define B_ 2
#define S_ 2048
#define E_ 4096
#define H_ 32
#define KV_ 8
#define D_ 128

typedef __bf16 v8bf __attribute__((ext_vector_type(8)));
typedef __bf16 v4bf __attribute__((ext_vector_type(4)));
typedef float  v4f  __attribute__((ext_vector_type(4)));

static __device__ __forceinline__ v4f mfma16(v8bf a, v8bf b, v4f c) {
    return __builtin_amdgcn_mfma_f32_16x16x32_bf16(a, b, c, 0, 0, 0);
}

// async global->LDS, 16B per lane; LDS dest = wave-uniform base + lane*16
static __device__ __forceinline__ void load_lds16(const void* g, void* l) {
    __builtin_amdgcn_global_load_lds(
        (const __attribute__((address_space(1))) void*)g,
        (__attribute__((address_space(3))) void*)l, 16, 0, 0);
}

// ---------------- cast fp32 -> bf16 (vectorized) ----------------
__global__ __launch_bounds__(256) void cast_f32_to_bf16(
        const float4* __restrict__ in, v4bf* __restrict__ out, int n4) {
    int i = blockIdx.x * blockDim.x + threadIdx.x;
    if (i >= n4) return;
    float4 v = in[i];
    v4bf o;
    o[0] = (__bf16)v.x; o[1] = (__bf16)v.y; o[2] = (__bf16)v.z; o[3] = (__bf16)v.w;
    out[i] = o;
}

// ---------------- in-place RoPE on bf16 (B,S,nh*128), optional prescale -----
__global__ __launch_bounds__(256) void rope_inplace(
        __bf16* __restrict__ qk, const int* __restrict__ pos, int nh,
        int rowstride, float outscale) {
    int idx = blockIdx.x * blockDim.x + threadIdx.x;
    int d = idx & 63;
    int t = idx >> 6;
    int h = t % nh;
    int bs = t / nh;
    if (bs >= B_ * S_) return;
    int s = bs & (S_ - 1);
    float p = (float)pos[s];
    float inv = expf(-(float)d * (1.0f / 64.0f) * 13.122363377404329f);
    float ang = p * inv;
    float c = cosf(ang), sn = sinf(ang);
    size_t off = (size_t)bs * rowstride + (size_t)h * D_;
    float x1 = (float)qk[off + d];
    float x2 = (float)qk[off + d + 64];
    qk[off + d]      = (__bf16)((x1 * c - x2 * sn) * outscale);
    qk[off + d + 64] = (__bf16)((x2 * c + x1 * sn) * outscale);
}

// ---------------- GEMM 256x256/BK=64, 8 waves, phase-split (round-3) --------
template <int EPI>
__global__ __launch_bounds__(512, 2) void gemm_bt(
        const __bf16* __restrict__ A, const __bf16* __restrict__ Bm,
        void* __restrict__ Cv, void* __restrict__ Cv2, int M, int N, int K) {
    __shared__ __bf16 As[2][256 * 64];
    __shared__ __bf16 Bs[2][256 * 64];
    const int tid  = threadIdx.x;
    const int wave = tid >> 6;
    const int lane = tid & 63;
    const int l15  = lane & 15;
    const int quad = lane >> 4;

    // XCD-chunked block swizzle (nwg % 8 == 0 for all our launches)
    const int nbx = N >> 8;
    const int nwg = (int)gridDim.x;
    const int swz = ((int)blockIdx.x & 7) * (nwg >> 3) + ((int)blockIdx.x >> 3);
    const int bm  = (swz / nbx) * 256;
    const int bn  = (swz % nbx) * 256;

    const int wr = wave >> 2;    // 0..1  (row group: 128 rows)
    const int wc = wave & 3;     // 0..3  (col group: 64 cols)

    v4f acc[8][4] = {};

    const int srow = wave * 8 + (lane >> 3);
    const int scc  = (lane & 7) ^ ((lane >> 3) & 7);

    auto stage = [&](int t, int buf) {
        const size_t k0 = (size_t)t * 64;
#pragma unroll
        for (int g = 0; g < 4; ++g) {
            load_lds16(A + (size_t)(bm + g * 64 + srow) * K + k0 + scc * 8,
                       (char*)&As[buf][0] + (size_t)g * 8192 + (size_t)wave * 1024);
            load_lds16(Bm + (size_t)(bn + g * 64 + srow) * K + k0 + scc * 8,
                       (char*)&Bs[buf][0] + (size_t)g * 8192 + (size_t)wave * 1024);
        }
    };

    stage(0, 0);   // prologue

    const int nt = K >> 6;
    for (int t = 0; t < nt; ++t) {
        const int cur = t & 1;
        if (t + 1 < nt) {
            stage(t + 1, cur ^ 1);
            asm volatile("s_waitcnt vmcnt(8)" ::: "memory");
        } else {
            asm volatile("s_waitcnt vmcnt(0)" ::: "memory");
        }
        __builtin_amdgcn_s_barrier();
        __builtin_amdgcn_sched_barrier(0);

        const __bf16* Asc = &As[cur][0];
        const __bf16* Bsc = &Bs[cur][0];
        v8bf a[4][2], b[2][2];

        auto rdA = [&](int mh) {
#pragma unroll
            for (int i = 0; i < 4; ++i)
#pragma unroll
                for (int kk = 0; kk < 2; ++kk)
                    a[i][kk] = *(const v8bf*)&Asc[
                        (wr * 128 + mh * 64 + i * 16 + l15) * 64 +
                        (((kk * 4 + quad) ^ (l15 & 7)) * 8)];
        };
        auto rdB = [&](int nh) {
#pragma unroll
            for (int j = 0; j < 2; ++j)
#pragma unroll
                for (int kk = 0; kk < 2; ++kk)
                    b[j][kk] = *(const v8bf*)&Bsc[
                        (wc * 64 + nh * 32 + j * 16 + l15) * 64 +
                        (((kk * 4 + quad) ^ (l15 & 7)) * 8)];
        };
        auto domfma = [&](int mh, int nh) {
            __builtin_amdgcn_s_setprio(1);
#pragma unroll
            for (int kk = 0; kk < 2; ++kk)
#pragma unroll
                for (int i = 0; i < 4; ++i)
#pragma unroll
                    for (int j = 0; j < 2; ++j)
                        acc[mh * 4 + i][nh * 2 + j] =
                            mfma16(a[i][kk], b[j][kk], acc[mh * 4 + i][nh * 2 + j]);
            __builtin_amdgcn_s_setprio(0);
        };

        // phase 0: (mh0, nh0)
        rdA(0); rdB(0);
        __builtin_amdgcn_s_barrier();
        domfma(0, 0);
        __builtin_amdgcn_s_barrier();
        __builtin_amdgcn_sched_barrier(0);
        // phase 1: (mh0, nh1) — reuse A
        rdB(1);
        __builtin_amdgcn_s_barrier();
        domfma(0, 1);
        __builtin_amdgcn_s_barrier();
        __builtin_amdgcn_sched_barrier(0);
        // phase 2: (mh1, nh1) — reuse B
        rdA(1);
        __builtin_amdgcn_s_barrier();
        domfma(1, 1);
        __builtin_amdgcn_s_barrier();
        __builtin_amdgcn_sched_barrier(0);
        // phase 3: (mh1, nh0)
        rdB(0);
        __builtin_amdgcn_s_barrier();
        domfma(1, 0);
        __builtin_amdgcn_s_barrier();
        __builtin_amdgcn_sched_barrier(0);
    }

    // epilogue: C/D layout col = lane&15, row = quad*4 + r (m89/m91 verified)
#pragma unroll
    for (int mi = 0; mi < 8; ++mi) {
#pragma unroll
        for (int nj = 0; nj < 4; ++nj) {
#pragma unroll
            for (int r = 0; r < 4; ++r) {
                int row = bm + wr * 128 + mi * 16 + quad * 4 + r;
                int col = bn + wc * 64 + nj * 16 + l15;
                float val = acc[mi][nj][r];
                if (EPI == 0) {
                    ((float*)Cv)[(size_t)row * N + col] = val;
                } else if (EPI == 1) {
                    ((__bf16*)Cv)[(size_t)row * N + col] = (__bf16)val;
                } else {
                    if (col < 1024) {
                        ((__bf16*)Cv)[(size_t)row * 1024 + col] = (__bf16)val;
                    } else {
                        int cc = col - 1024;
                        int b  = row >> 11, s = row & (S_ - 1);
                        int kv = cc >> 7,  d = cc & (D_ - 1);
                        ((__bf16*)Cv2)[((size_t)((b * KV_ + kv) * D_ + d)) * S_ + s] = (__bf16)val;
                    }
                }
            }
        }
    }
}

// ---------------- fused causal flash attention (swapped-QK softmax) ---------
// q: (B,S,E) bf16 roped+prescaled by 1/sqrt(D); k: (B,S,KV*D) bf16 roped;
// vt: (B,KV,D,S) bf16.  Block = 4 waves = 64 queries of one (b,h).
// K/V^T 64-key tiles double-buffered in LDS (verified XOR chunk swizzles),
// counted vmcnt(8) pipeline (round-2 verified).
// QK^T computed SWAPPED: s = mfma(Kfrag, Qfrag) -> C[row=key][col=query],
// so each lane holds 16 keys of ONE query (l15): row max/sum are 15 local
// VALU ops + 2 shfl steps (xor 16,32) instead of 2x4-step trees (T12 idea).
// T13 defer-max (THR=8) skips the o-rescale when the running max grows <8.
// P written as 4x ds_write_b64, chunk-XOR swizzled (round-4: 0 conflicts).
__global__ __launch_bounds__(256, 2) void attn_fused(
        const __bf16* __restrict__ q, const __bf16* __restrict__ k,
        const __bf16* __restrict__ vt, __bf16* __restrict__ attn) {
    __shared__ __bf16 Ks[2][64 * 128];   // [key][d], chunk16 c at c^(key&15)
    __shared__ __bf16 Vs[2][128 * 64];   // [d][key], chunk16 c at c^(d&7)
    __shared__ __bf16 P[4][16 * 64];     // per-wave P, chunk8 c at c^(row&7)
    const int wave = threadIdx.x >> 6;
    const int lane = threadIdx.x & 63;

    // XCD-aware decode: each XCD owns bh in [xcd*8, xcd*8+8) -> 2MB K/V
    // working set per XCD L2 (verified: FETCH 79.6 -> 24.6 MB).
    const int wgid = blockIdx.x;
    const int xcd  = wgid & 7;
    const int slot = wgid >> 3;               // 0..255
    const int bh   = xcd * 8 + (slot >> 5);   // 8 bh per XCD
    const int qblk = 31 - (slot & 31);        // long blocks first
    const int b = bh >> 5;       // H=32
    const int h = bh & 31;
    const int kvh = h >> 2;      // rep = H/KV = 4
    const int q0 = qblk * 64 + wave * 16;
    const int l15  = lane & 15;
    const int quad = lane >> 4;

    const __bf16* qbase = q  + (size_t)(b * S_) * E_ + (size_t)h * D_;
    const __bf16* kbase = k  + (size_t)(b * S_) * (KV_ * D_) + (size_t)kvh * D_;
    const __bf16* vbase = vt + (size_t)((b * KV_ + kvh) * D_) * S_;
    __bf16* Pw = &P[wave][0];

    const int krow_l = lane >> 4;
    const int kcc    = lane & 15;
    const int vrow_l = lane >> 3;
    const int vcc    = lane & 7;

    auto stageK = [&](int t, int buf) {
#pragma unroll
        for (int i = 0; i < 4; ++i) {
            int g = wave * 4 + i;
            int row = g * 4 + krow_l;
            int scc = kcc ^ (row & 15);
            load_lds16(kbase + (size_t)(t * 64 + row) * (KV_ * D_) + scc * 8,
                       (char*)&Ks[buf][0] + (size_t)g * 1024);
        }
    };
    auto stageV = [&](int t, int buf) {
#pragma unroll
        for (int i = 0; i < 4; ++i) {
            int g = wave * 4 + i;
            int row = g * 8 + vrow_l;
            int scc = vcc ^ (row & 7);
            load_lds16(vbase + (size_t)row * S_ + t * 64 + scc * 8,
                       (char*)&Vs[buf][0] + (size_t)g * 1024);
        }
    };

    stageK(0, 0);
    stageV(0, 0);

    v8bf aq[4];
#pragma unroll
    for (int kc = 0; kc < 4; ++kc)
        aq[kc] = *(const v8bf*)(qbase + (size_t)(q0 + l15) * E_ + kc * 32 + quad * 8);

    v4f o[8] = {};
    float m_i = -INFINITY, l_i = 0.f;   // per-lane state for query q0 + l15

    const int ntiles = qblk + 1;        // block-uniform

    for (int t = 0; t < ntiles; ++t) {
        const int cur = t & 1;
        if (t + 1 < ntiles) {
            stageK(t + 1, cur ^ 1);
            stageV(t + 1, cur ^ 1);
            asm volatile("s_waitcnt vmcnt(8)" ::: "memory");
        } else {
            asm volatile("s_waitcnt vmcnt(0)" ::: "memory");
        }
        __builtin_amdgcn_s_barrier();
        __builtin_amdgcn_sched_barrier(0);

        const int n0 = t * 64;
        const __bf16* Ksc = &Ks[cur][0];
        const __bf16* Vsc = &Vs[cur][0];

        // ---- QK^T swapped: C[row = key quad*4+r (+16j)][col = query l15] ----
        v4f s[4] = {};
        __builtin_amdgcn_s_setprio(1);
#pragma unroll
        for (int kc = 0; kc < 4; ++kc) {
            v8bf kf[4];
#pragma unroll
            for (int j = 0; j < 4; ++j)
                kf[j] = *(const v8bf*)&Ksc[(j * 16 + l15) * 128 +
                                           (((kc * 4 + quad) ^ l15) * 8)];
#pragma unroll
            for (int j = 0; j < 4; ++j)
                s[j] = mfma16(kf[j], aq[kc], s[j]);   // A=K, B=Q
        }
        __builtin_amdgcn_s_setprio(0);

        // ---- (boundary-only) causal mask: key > query -> -inf ----
        float e[4][4];
        if (n0 + 63 > q0) {           // wave-uniform
#pragma unroll
            for (int j = 0; j < 4; ++j)
#pragma unroll
                for (int r = 0; r < 4; ++r) {
                    float v = s[j][r];
                    if (n0 + j * 16 + quad * 4 + r > q0 + l15) v = -INFINITY;
                    e[j][r] = v;
                }
        } else {
#pragma unroll
            for (int j = 0; j < 4; ++j)
#pragma unroll
                for (int r = 0; r < 4; ++r)
                    e[j][r] = s[j][r];
        }

        // ---- online softmax: row is lane-local (16 vals) + 2 shfl steps ----
        float mloc = e[0][0];
#pragma unroll
        for (int j = 0; j < 4; ++j)
#pragma unroll
            for (int r = 0; r < 4; ++r)
                mloc = fmaxf(mloc, e[j][r]);
        mloc = fmaxf(mloc, __shfl_xor(mloc, 16, 64));
        mloc = fmaxf(mloc, __shfl_xor(mloc, 32, 64));

        // T13 defer-max: only rescale when the max grew by more than THR=8
        if (!__all(mloc - m_i <= 8.0f)) {
            float mnew = fmaxf(m_i, mloc);
            float alpha = __expf(m_i - mnew);   // exp(-inf)=0 on first tile
            m_i = mnew;
            l_i *= alpha;
            float af[4];
#pragma unroll
            for (int r = 0; r < 4; ++r)
                af[r] = __shfl(alpha, quad * 4 + r, 16);
#pragma unroll
            for (int c = 0; c < 8; ++c)
#pragma unroll
                for (int r = 0; r < 4; ++r)
                    o[c][r] *= af[r];
        }

        float psum = 0.f;
#pragma unroll
        for (int j = 0; j < 4; ++j)
#pragma unroll
            for (int r = 0; r < 4; ++r) {
                e[j][r] = __expf(e[j][r] - m_i);
                psum += e[j][r];
            }
        psum += __shfl_xor(psum, 16, 64);
        psum += __shfl_xor(psum, 32, 64);
        l_i += psum;

        // ---- P write: row = l15 (query), cols 16j + 4*quad + r, packed b64,
        //      chunk-XOR swizzle (stored chunk = logical ^ (row&7)) ----
#pragma unroll
        for (int j = 0; j < 4; ++j) {
            v4bf pk;
#pragma unroll
            for (int r = 0; r < 4; ++r) pk[r] = (__bf16)e[j][r];
            int cl = j * 2 + (quad >> 1);
            *(v4bf*)&Pw[l15 * 64 + ((cl ^ (l15 & 7)) << 3) + ((quad & 1) << 2)] = pk;
        }

        // re-read as A-fragment: row l15, logical chunks quad / 4+quad
        v8bf ap0 = *(const v8bf*)&Pw[l15 * 64 + ((quad ^ (l15 & 7)) << 3)];
        v8bf ap1 = *(const v8bf*)&Pw[l15 * 64 + (((4 + quad) ^ (l15 & 7)) << 3)];

        // ---- PV: o[d-tile] += P * V^T, V from LDS ----
        __builtin_amdgcn_s_setprio(1);
#pragma unroll
        for (int c = 0; c < 8; ++c) {
            v8bf v0 = *(const v8bf*)&Vsc[(c * 16 + l15) * 64 +
                                         ((quad ^ (l15 & 7)) * 8)];
            v8bf v1 = *(const v8bf*)&Vsc[(c * 16 + l15) * 64 +
                                         (((4 + quad) ^ (l15 & 7)) * 8)];
            o[c] = mfma16(ap0, v0, o[c]);
            o[c] = mfma16(ap1, v1, o[c]);
        }
        __builtin_amdgcn_s_setprio(0);

        __builtin_amdgcn_sched_barrier(0);
        asm volatile("s_waitcnt lgkmcnt(0)" ::: "memory");
        __builtin_amdgcn_s_barrier();
        __builtin_amdgcn_sched_barrier(0);
    }

    float linv = 1.0f / l_i;     // for query q0 + l15
    float lr[4];
#pragma unroll
    for (int r = 0; r < 4; ++r)
        lr[r] = __shfl(linv, quad * 4 + r, 16);
    __bf16* obase = attn + (size_t)(b * S_) * E_ + (size_t)h * D_;
#pragma unroll
    for (int c = 0; c < 8; ++c)
#pragma unroll
        for (int r = 0; r < 4; ++r)
            obase[(size_t)(q0 + quad * 4 + r) * E_ + c * 16 + l15] =
                (__bf16)(o[c][r] * lr[r]);
}

extern "C" void kernel_launch(void* const* d_in, const int* in_sizes, int n_in,
                              void* d_out, int out_size, void* d_ws, size_t ws_size,
                              hipStream_t stream) {
    (void)in_sizes; (void)n_in; (void)out_size; (void)ws_size;
    const float* x  = (const float*)d_in[0];
    const float* wq = (const float*)d_in[1];
    const float* wk = (const float*)d_in[2];
    const float* wv = (const float*)d_in[3];
    const float* wo = (const float*)d_in[4];
    const int*   pos = (const int*)d_in[5];
    float* out = (float*)d_out;

    char* ws = (char*)d_ws;
    size_t off = 0;
    auto alloc = [&](size_t bytes) {
        char* p = ws + off;
        off += (bytes + 255) & ~(size_t)255;
        return p;
    };
    __bf16* xb   = (__bf16*)alloc((size_t)B_ * S_ * E_ * 2);
    __bf16* wqb  = (__bf16*)alloc((size_t)E_ * E_ * 2);
    __bf16* wkvb = (__bf16*)alloc((size_t)2 * KV_ * D_ * E_ * 2);  // [wk;wv] rows
    __bf16* wob  = (__bf16*)alloc((size_t)E_ * E_ * 2);
    __bf16* qb   = (__bf16*)alloc((size_t)B_ * S_ * E_ * 2);
    __bf16* kb   = (__bf16*)alloc((size_t)B_ * S_ * KV_ * D_ * 2);
    __bf16* vt   = (__bf16*)alloc((size_t)B_ * KV_ * D_ * S_ * 2);
    __bf16* at   = (__bf16*)alloc((size_t)B_ * S_ * E_ * 2);

    auto cast = [&](const float* in, __bf16* ob, size_t n) {
        int n4 = (int)(n / 4);
        cast_f32_to_bf16<<<(n4 + 255) / 256, 256, 0, stream>>>(
            (const float4*)in, (v4bf*)ob, n4);
    };
    cast(x,  xb,  (size_t)B_ * S_ * E_);
    cast(wq, wqb, (size_t)E_ * E_);
    cast(wk, wkvb, (size_t)KV_ * D_ * E_);
    cast(wv, wkvb + (size_t)KV_ * D_ * E_, (size_t)KV_ * D_ * E_);
    cast(wo, wob, (size_t)E_ * E_);

    const int M = B_ * S_;
    const int nwg_e = (E_ / 256) * (M / 256);            // 256
    const int nwg_kv = (2 * KV_ * D_ / 256) * (M / 256); // 128
    gemm_bt<1><<<dim3(nwg_e), 512, 0, stream>>>(
        xb, wqb, qb, nullptr, M, E_, E_);
    gemm_bt<2><<<dim3(nwg_kv), 512, 0, stream>>>(
        xb, wkvb, kb, vt, M, 2 * KV_ * D_, E_);

    // q gets RoPE + 1/sqrt(D) prescale (fp32 math); k gets RoPE only.
    rope_inplace<<<(B_ * S_ * H_ * 64 + 255) / 256, 256, 0, stream>>>(
        qb, pos, H_, E_, 0.08838834764831845f);
    rope_inplace<<<(B_ * S_ * KV_ * 64 + 255) / 256, 256, 0, stream>>>(
        kb, pos, KV_, KV_ * D_, 1.0f);

    attn_fused<<<dim3(B_ * H_ * (S_ / 64)), 256, 0, stream>>>(qb, kb, vt, at);

    gemm_bt<0><<<dim3(nwg_e), 512, 0, stream>>>(
        at, wob, out, nullptr, M, E_, E_);
}

// Round 6
// 816.094 us; speedup vs baseline: 1.2278x; 1.0895x over previous
//
#include <hip/hip_runtime.h>

#define B_ 2
#define S_ 2048
#define E_ 4096
#define H_ 32
#define KV_ 8
#define D_ 128

typedef __bf16 v8bf __attribute__((ext_vector_type(8)));
typedef __bf16 v4bf __attribute__((ext_vector_type(4)));
typedef float  v4f  __attribute__((ext_vector_type(4)));

static __device__ __forceinline__ v4f mfma16(v8bf a, v8bf b, v4f c) {
    return __builtin_amdgcn_mfma_f32_16x16x32_bf16(a, b, c, 0, 0, 0);
}

// async global->LDS, 16B per lane; LDS dest = wave-uniform base + lane*16
static __device__ __forceinline__ void load_lds16(const void* g, void* l) {
    __builtin_amdgcn_global_load_lds(
        (const __attribute__((address_space(1))) void*)g,
        (__attribute__((address_space(3))) void*)l, 16, 0, 0);
}

// ---------------- cast fp32 -> bf16 (vectorized) ----------------
__global__ __launch_bounds__(256) void cast_f32_to_bf16(
        const float4* __restrict__ in, v4bf* __restrict__ out, int n4) {
    int i = blockIdx.x * blockDim.x + threadIdx.x;
    if (i >= n4) return;
    float4 v = in[i];
    v4bf o;
    o[0] = (__bf16)v.x; o[1] = (__bf16)v.y; o[2] = (__bf16)v.z; o[3] = (__bf16)v.w;
    out[i] = o;
}

// ---------------- in-place RoPE on bf16 (B,S,nh*128), optional prescale -----
__global__ __launch_bounds__(256) void rope_inplace(
        __bf16* __restrict__ qk, const int* __restrict__ pos, int nh,
        int rowstride, float outscale) {
    int idx = blockIdx.x * blockDim.x + threadIdx.x;
    int d = idx & 63;
    int t = idx >> 6;
    int h = t % nh;
    int bs = t / nh;
    if (bs >= B_ * S_) return;
    int s = bs & (S_ - 1);
    float p = (float)pos[s];
    float inv = expf(-(float)d * (1.0f / 64.0f) * 13.122363377404329f);
    float ang = p * inv;
    float c = cosf(ang), sn = sinf(ang);
    size_t off = (size_t)bs * rowstride + (size_t)h * D_;
    float x1 = (float)qk[off + d];
    float x2 = (float)qk[off + d + 64];
    qk[off + d]      = (__bf16)((x1 * c - x2 * sn) * outscale);
    qk[off + d + 64] = (__bf16)((x2 * c + x1 * sn) * outscale);
}

// ---------------- GEMM 256x256/BK=64, 8 waves, free-scheduled body ----------
// C[M,N] = A[M,K] * B[N,K]^T, bf16 in, fp32 acc.
// Tile-boundary protocol (verified r2/r5): stage tile t+1 -> counted vmcnt(8)
// -> barrier -> body -> lgkmcnt(0) -> barrier. NO intra-tile barriers: within
// an iteration the LDS buffers are read-only (staging writes the other dbuf;
// the only WAR hazard, tile t+2 overwriting buf[cur], is guarded by the
// bottom lgkmcnt+barrier). De-lockstepping lets waves drift so one wave's
// MFMAs cover another's ds_reads (m114 overlap); register headroom is free
// (1 block/CU: LDS-capped at 2 waves/SIMD, VGPR cap 256).
template <int EPI>
__global__ __launch_bounds__(512, 2) void gemm_bt(
        const __bf16* __restrict__ A, const __bf16* __restrict__ Bm,
        void* __restrict__ Cv, void* __restrict__ Cv2, int M, int N, int K) {
    __shared__ __bf16 As[2][256 * 64];
    __shared__ __bf16 Bs[2][256 * 64];
    const int tid  = threadIdx.x;
    const int wave = tid >> 6;
    const int lane = tid & 63;
    const int l15  = lane & 15;
    const int quad = lane >> 4;

    // XCD-chunked block swizzle (nwg % 8 == 0 for all our launches)
    const int nbx = N >> 8;
    const int nwg = (int)gridDim.x;
    const int swz = ((int)blockIdx.x & 7) * (nwg >> 3) + ((int)blockIdx.x >> 3);
    const int bm  = (swz / nbx) * 256;
    const int bn  = (swz % nbx) * 256;

    const int wr = wave >> 2;    // 0..1  (row group: 128 rows)
    const int wc = wave & 3;     // 0..3  (col group: 64 cols)

    v4f acc[8][4] = {};

    const int srow = wave * 8 + (lane >> 3);
    const int scc  = (lane & 7) ^ ((lane >> 3) & 7);

    auto stage = [&](int t, int buf) {
        const size_t k0 = (size_t)t * 64;
#pragma unroll
        for (int g = 0; g < 4; ++g) {
            load_lds16(A + (size_t)(bm + g * 64 + srow) * K + k0 + scc * 8,
                       (char*)&As[buf][0] + (size_t)g * 8192 + (size_t)wave * 1024);
            load_lds16(Bm + (size_t)(bn + g * 64 + srow) * K + k0 + scc * 8,
                       (char*)&Bs[buf][0] + (size_t)g * 8192 + (size_t)wave * 1024);
        }
    };

    stage(0, 0);   // prologue

    const int nt = K >> 6;
    for (int t = 0; t < nt; ++t) {
        const int cur = t & 1;
        if (t + 1 < nt) {
            stage(t + 1, cur ^ 1);
            asm volatile("s_waitcnt vmcnt(8)" ::: "memory");
        } else {
            asm volatile("s_waitcnt vmcnt(0)" ::: "memory");
        }
        __builtin_amdgcn_s_barrier();
        __builtin_amdgcn_sched_barrier(0);

        const __bf16* Asc = &As[cur][0];
        const __bf16* Bsc = &Bs[cur][0];
        v8bf a[4][2], b0[2][2], b1[2][2];

        // A-half mh=0 + both B halves
#pragma unroll
        for (int i = 0; i < 4; ++i)
#pragma unroll
            for (int kk = 0; kk < 2; ++kk)
                a[i][kk] = *(const v8bf*)&Asc[
                    (wr * 128 + i * 16 + l15) * 64 +
                    (((kk * 4 + quad) ^ (l15 & 7)) * 8)];
#pragma unroll
        for (int j = 0; j < 2; ++j)
#pragma unroll
            for (int kk = 0; kk < 2; ++kk) {
                b0[j][kk] = *(const v8bf*)&Bsc[
                    (wc * 64 + j * 16 + l15) * 64 +
                    (((kk * 4 + quad) ^ (l15 & 7)) * 8)];
                b1[j][kk] = *(const v8bf*)&Bsc[
                    (wc * 64 + 32 + j * 16 + l15) * 64 +
                    (((kk * 4 + quad) ^ (l15 & 7)) * 8)];
            }

        __builtin_amdgcn_s_setprio(1);
#pragma unroll
        for (int kk = 0; kk < 2; ++kk)
#pragma unroll
            for (int i = 0; i < 4; ++i)
#pragma unroll
                for (int j = 0; j < 2; ++j)
                    acc[i][j] = mfma16(a[i][kk], b0[j][kk], acc[i][j]);
#pragma unroll
        for (int kk = 0; kk < 2; ++kk)
#pragma unroll
            for (int i = 0; i < 4; ++i)
#pragma unroll
                for (int j = 0; j < 2; ++j)
                    acc[i][2 + j] = mfma16(a[i][kk], b1[j][kk], acc[i][2 + j]);
        __builtin_amdgcn_s_setprio(0);

        // A-half mh=1 (reuses a[] registers)
#pragma unroll
        for (int i = 0; i < 4; ++i)
#pragma unroll
            for (int kk = 0; kk < 2; ++kk)
                a[i][kk] = *(const v8bf*)&Asc[
                    (wr * 128 + 64 + i * 16 + l15) * 64 +
                    (((kk * 4 + quad) ^ (l15 & 7)) * 8)];

        __builtin_amdgcn_s_setprio(1);
#pragma unroll
        for (int kk = 0; kk < 2; ++kk)
#pragma unroll
            for (int i = 0; i < 4; ++i)
#pragma unroll
                for (int j = 0; j < 2; ++j)
                    acc[4 + i][2 + j] = mfma16(a[i][kk], b1[j][kk], acc[4 + i][2 + j]);
#pragma unroll
        for (int kk = 0; kk < 2; ++kk)
#pragma unroll
            for (int i = 0; i < 4; ++i)
#pragma unroll
                for (int j = 0; j < 2; ++j)
                    acc[4 + i][j] = mfma16(a[i][kk], b0[j][kk], acc[4 + i][j]);
        __builtin_amdgcn_s_setprio(0);

        __builtin_amdgcn_sched_barrier(0);
        asm volatile("s_waitcnt lgkmcnt(0)" ::: "memory");
        __builtin_amdgcn_s_barrier();
        __builtin_amdgcn_sched_barrier(0);
    }

    // epilogue: C/D layout col = lane&15, row = quad*4 + r (m89/m91 verified)
#pragma unroll
    for (int mi = 0; mi < 8; ++mi) {
#pragma unroll
        for (int nj = 0; nj < 4; ++nj) {
#pragma unroll
            for (int r = 0; r < 4; ++r) {
                int row = bm + wr * 128 + mi * 16 + quad * 4 + r;
                int col = bn + wc * 64 + nj * 16 + l15;
                float val = acc[mi][nj][r];
                if (EPI == 0) {
                    ((float*)Cv)[(size_t)row * N + col] = val;
                } else if (EPI == 1) {
                    ((__bf16*)Cv)[(size_t)row * N + col] = (__bf16)val;
                } else {
                    if (col < 1024) {
                        ((__bf16*)Cv)[(size_t)row * 1024 + col] = (__bf16)val;
                    } else {
                        int cc = col - 1024;
                        int b  = row >> 11, s = row & (S_ - 1);
                        int kv = cc >> 7,  d = cc & (D_ - 1);
                        ((__bf16*)Cv2)[((size_t)((b * KV_ + kv) * D_ + d)) * S_ + s] = (__bf16)val;
                    }
                }
            }
        }
    }
}

// ---------------- fused causal flash attention (swapped-QK softmax) ---------
// (verified round 5: swapped QK^T lane-local softmax, defer-max THR=8,
// counted vmcnt dbuf staging, XCD-partitioned decode, 0-conflict P swizzle)
__global__ __launch_bounds__(256, 2) void attn_fused(
        const __bf16* __restrict__ q, const __bf16* __restrict__ k,
        const __bf16* __restrict__ vt, __bf16* __restrict__ attn) {
    __shared__ __bf16 Ks[2][64 * 128];   // [key][d], chunk16 c at c^(key&15)
    __shared__ __bf16 Vs[2][128 * 64];   // [d][key], chunk16 c at c^(d&7)
    __shared__ __bf16 P[4][16 * 64];     // per-wave P, chunk8 c at c^(row&7)
    const int wave = threadIdx.x >> 6;
    const int lane = threadIdx.x & 63;

    const int wgid = blockIdx.x;
    const int xcd  = wgid & 7;
    const int slot = wgid >> 3;               // 0..255
    const int bh   = xcd * 8 + (slot >> 5);   // 8 bh per XCD
    const int qblk = 31 - (slot & 31);        // long blocks first
    const int b = bh >> 5;       // H=32
    const int h = bh & 31;
    const int kvh = h >> 2;      // rep = H/KV = 4
    const int q0 = qblk * 64 + wave * 16;
    const int l15  = lane & 15;
    const int quad = lane >> 4;

    const __bf16* qbase = q  + (size_t)(b * S_) * E_ + (size_t)h * D_;
    const __bf16* kbase = k  + (size_t)(b * S_) * (KV_ * D_) + (size_t)kvh * D_;
    const __bf16* vbase = vt + (size_t)((b * KV_ + kvh) * D_) * S_;
    __bf16* Pw = &P[wave][0];

    const int krow_l = lane >> 4;
    const int kcc    = lane & 15;
    const int vrow_l = lane >> 3;
    const int vcc    = lane & 7;

    auto stageK = [&](int t, int buf) {
#pragma unroll
        for (int i = 0; i < 4; ++i) {
            int g = wave * 4 + i;
            int row = g * 4 + krow_l;
            int scc = kcc ^ (row & 15);
            load_lds16(kbase + (size_t)(t * 64 + row) * (KV_ * D_) + scc * 8,
                       (char*)&Ks[buf][0] + (size_t)g * 1024);
        }
    };
    auto stageV = [&](int t, int buf) {
#pragma unroll
        for (int i = 0; i < 4; ++i) {
            int g = wave * 4 + i;
            int row = g * 8 + vrow_l;
            int scc = vcc ^ (row & 7);
            load_lds16(vbase + (size_t)row * S_ + t * 64 + scc * 8,
                       (char*)&Vs[buf][0] + (size_t)g * 1024);
        }
    };

    stageK(0, 0);
    stageV(0, 0);

    v8bf aq[4];
#pragma unroll
    for (int kc = 0; kc < 4; ++kc)
        aq[kc] = *(const v8bf*)(qbase + (size_t)(q0 + l15) * E_ + kc * 32 + quad * 8);

    v4f o[8] = {};
    float m_i = -INFINITY, l_i = 0.f;   // per-lane state for query q0 + l15

    const int ntiles = qblk + 1;        // block-uniform

    for (int t = 0; t < ntiles; ++t) {
        const int cur = t & 1;
        if (t + 1 < ntiles) {
            stageK(t + 1, cur ^ 1);
            stageV(t + 1, cur ^ 1);
            asm volatile("s_waitcnt vmcnt(8)" ::: "memory");
        } else {
            asm volatile("s_waitcnt vmcnt(0)" ::: "memory");
        }
        __builtin_amdgcn_s_barrier();
        __builtin_amdgcn_sched_barrier(0);

        const int n0 = t * 64;
        const __bf16* Ksc = &Ks[cur][0];
        const __bf16* Vsc = &Vs[cur][0];

        // ---- QK^T swapped: C[row = key quad*4+r (+16j)][col = query l15] ----
        v4f s[4] = {};
        __builtin_amdgcn_s_setprio(1);
#pragma unroll
        for (int kc = 0; kc < 4; ++kc) {
            v8bf kf[4];
#pragma unroll
            for (int j = 0; j < 4; ++j)
                kf[j] = *(const v8bf*)&Ksc[(j * 16 + l15) * 128 +
                                           (((kc * 4 + quad) ^ l15) * 8)];
#pragma unroll
            for (int j = 0; j < 4; ++j)
                s[j] = mfma16(kf[j], aq[kc], s[j]);   // A=K, B=Q
        }
        __builtin_amdgcn_s_setprio(0);

        // ---- (boundary-only) causal mask: key > query -> -inf ----
        float e[4][4];
        if (n0 + 63 > q0) {           // wave-uniform
#pragma unroll
            for (int j = 0; j < 4; ++j)
#pragma unroll
                for (int r = 0; r < 4; ++r) {
                    float v = s[j][r];
                    if (n0 + j * 16 + quad * 4 + r > q0 + l15) v = -INFINITY;
                    e[j][r] = v;
                }
        } else {
#pragma unroll
            for (int j = 0; j < 4; ++j)
#pragma unroll
                for (int r = 0; r < 4; ++r)
                    e[j][r] = s[j][r];
        }

        // ---- online softmax: row is lane-local (16 vals) + 2 shfl steps ----
        float mloc = e[0][0];
#pragma unroll
        for (int j = 0; j < 4; ++j)
#pragma unroll
            for (int r = 0; r < 4; ++r)
                mloc = fmaxf(mloc, e[j][r]);
        mloc = fmaxf(mloc, __shfl_xor(mloc, 16, 64));
        mloc = fmaxf(mloc, __shfl_xor(mloc, 32, 64));

        // T13 defer-max: only rescale when the max grew by more than THR=8
        if (!__all(mloc - m_i <= 8.0f)) {
            float mnew = fmaxf(m_i, mloc);
            float alpha = __expf(m_i - mnew);   // exp(-inf)=0 on first tile
            m_i = mnew;
            l_i *= alpha;
            float af[4];
#pragma unroll
            for (int r = 0; r < 4; ++r)
                af[r] = __shfl(alpha, quad * 4 + r, 16);
#pragma unroll
            for (int c = 0; c < 8; ++c)
#pragma unroll
                for (int r = 0; r < 4; ++r)
                    o[c][r] *= af[r];
        }

        float psum = 0.f;
#pragma unroll
        for (int j = 0; j < 4; ++j)
#pragma unroll
            for (int r = 0; r < 4; ++r) {
                e[j][r] = __expf(e[j][r] - m_i);
                psum += e[j][r];
            }
        psum += __shfl_xor(psum, 16, 64);
        psum += __shfl_xor(psum, 32, 64);
        l_i += psum;

        // ---- P write: row = l15 (query), cols 16j + 4*quad + r, packed b64,
        //      chunk-XOR swizzle (stored chunk = logical ^ (row&7)) ----
#pragma unroll
        for (int j = 0; j < 4; ++j) {
            v4bf pk;
#pragma unroll
            for (int r = 0; r < 4; ++r) pk[r] = (__bf16)e[j][r];
            int cl = j * 2 + (quad >> 1);
            *(v4bf*)&Pw[l15 * 64 + ((cl ^ (l15 & 7)) << 3) + ((quad & 1) << 2)] = pk;
        }

        // re-read as A-fragment: row l15, logical chunks quad / 4+quad
        v8bf ap0 = *(const v8bf*)&Pw[l15 * 64 + ((quad ^ (l15 & 7)) << 3)];
        v8bf ap1 = *(const v8bf*)&Pw[l15 * 64 + (((4 + quad) ^ (l15 & 7)) << 3)];

        // ---- PV: o[d-tile] += P * V^T, V from LDS ----
        __builtin_amdgcn_s_setprio(1);
#pragma unroll
        for (int c = 0; c < 8; ++c) {
            v8bf v0 = *(const v8bf*)&Vsc[(c * 16 + l15) * 64 +
                                         ((quad ^ (l15 & 7)) * 8)];
            v8bf v1 = *(const v8bf*)&Vsc[(c * 16 + l15) * 64 +
                                         (((4 + quad) ^ (l15 & 7)) * 8)];
            o[c] = mfma16(ap0, v0, o[c]);
            o[c] = mfma16(ap1, v1, o[c]);
        }
        __builtin_amdgcn_s_setprio(0);

        __builtin_amdgcn_sched_barrier(0);
        asm volatile("s_waitcnt lgkmcnt(0)" ::: "memory");
        __builtin_amdgcn_s_barrier();
        __builtin_amdgcn_sched_barrier(0);
    }

    float linv = 1.0f / l_i;     // for query q0 + l15
    float lr[4];
#pragma unroll
    for (int r = 0; r < 4; ++r)
        lr[r] = __shfl(linv, quad * 4 + r, 16);
    __bf16* obase = attn + (size_t)(b * S_) * E_ + (size_t)h * D_;
#pragma unroll
    for (int c = 0; c < 8; ++c)
#pragma unroll
        for (int r = 0; r < 4; ++r)
            obase[(size_t)(q0 + quad * 4 + r) * E_ + c * 16 + l15] =
                (__bf16)(o[c][r] * lr[r]);
}

extern "C" void kernel_launch(void* const* d_in, const int* in_sizes, int n_in,
                              void* d_out, int out_size, void* d_ws, size_t ws_size,
                              hipStream_t stream) {
    (void)in_sizes; (void)n_in; (void)out_size; (void)ws_size;
    const float* x  = (const float*)d_in[0];
    const float* wq = (const float*)d_in[1];
    const float* wk = (const float*)d_in[2];
    const float* wv = (const float*)d_in[3];
    const float* wo = (const float*)d_in[4];
    const int*   pos = (const int*)d_in[5];
    float* out = (float*)d_out;

    char* ws = (char*)d_ws;
    size_t off = 0;
    auto alloc = [&](size_t bytes) {
        char* p = ws + off;
        off += (bytes + 255) & ~(size_t)255;
        return p;
    };
    __bf16* xb   = (__bf16*)alloc((size_t)B_ * S_ * E_ * 2);
    __bf16* wqb  = (__bf16*)alloc((size_t)E_ * E_ * 2);
    __bf16* wkvb = (__bf16*)alloc((size_t)2 * KV_ * D_ * E_ * 2);  // [wk;wv] rows
    __bf16* wob  = (__bf16*)alloc((size_t)E_ * E_ * 2);
    __bf16* qb   = (__bf16*)alloc((size_t)B_ * S_ * E_ * 2);
    __bf16* kb   = (__bf16*)alloc((size_t)B_ * S_ * KV_ * D_ * 2);
    __bf16* vt   = (__bf16*)alloc((size_t)B_ * KV_ * D_ * S_ * 2);
    __bf16* at   = (__bf16*)alloc((size_t)B_ * S_ * E_ * 2);

    auto cast = [&](const float* in, __bf16* ob, size_t n) {
        int n4 = (int)(n / 4);
        cast_f32_to_bf16<<<(n4 + 255) / 256, 256, 0, stream>>>(
            (const float4*)in, (v4bf*)ob, n4);
    };
    cast(x,  xb,  (size_t)B_ * S_ * E_);
    cast(wq, wqb, (size_t)E_ * E_);
    cast(wk, wkvb, (size_t)KV_ * D_ * E_);
    cast(wv, wkvb + (size_t)KV_ * D_ * E_, (size_t)KV_ * D_ * E_);
    cast(wo, wob, (size_t)E_ * E_);

    const int M = B_ * S_;
    const int nwg_e = (E_ / 256) * (M / 256);            // 256
    const int nwg_kv = (2 * KV_ * D_ / 256) * (M / 256); // 128
    gemm_bt<1><<<dim3(nwg_e), 512, 0, stream>>>(
        xb, wqb, qb, nullptr, M, E_, E_);
    gemm_bt<2><<<dim3(nwg_kv), 512, 0, stream>>>(
        xb, wkvb, kb, vt, M, 2 * KV_ * D_, E_);

    // q gets RoPE + 1/sqrt(D) prescale (fp32 math); k gets RoPE only.
    rope_inplace<<<(B_ * S_ * H_ * 64 + 255) / 256, 256, 0, stream>>>(
        qb, pos, H_, E_, 0.08838834764831845f);
    rope_inplace<<<(B_ * S_ * KV_ * 64 + 255) / 256, 256, 0, stream>>>(
        kb, pos, KV_, KV_ * D_, 1.0f);

    attn_fused<<<dim3(B_ * H_ * (S_ / 64)), 256, 0, stream>>>(qb, kb, vt, at);

    gemm_bt<0><<<dim3(nwg_e), 512, 0, stream>>>(
        at, wob, out, nullptr, M, E_, E_);
}

// Round 8
// 764.355 us; speedup vs baseline: 1.3109x; 1.0677x over previous
//
#include <hip/hip_runtime.h>

#define B_ 2
#define S_ 2048
#define E_ 4096
#define H_ 32
#define KV_ 8
#define D_ 128

typedef __bf16 v8bf __attribute__((ext_vector_type(8)));
typedef __bf16 v4bf __attribute__((ext_vector_type(4)));
typedef float  v4f  __attribute__((ext_vector_type(4)));

static __device__ __forceinline__ v4f mfma16(v8bf a, v8bf b, v4f c) {
    return __builtin_amdgcn_mfma_f32_16x16x32_bf16(a, b, c, 0, 0, 0);
}

// async global->LDS, 16B per lane; LDS dest = wave-uniform base + lane*16
static __device__ __forceinline__ void load_lds16(const void* g, void* l) {
    __builtin_amdgcn_global_load_lds(
        (const __attribute__((address_space(1))) void*)g,
        (__attribute__((address_space(3))) void*)l, 16, 0, 0);
}

// ---------------- cast fp32 -> bf16 (vectorized) ----------------
__global__ __launch_bounds__(256) void cast_f32_to_bf16(
        const float4* __restrict__ in, v4bf* __restrict__ out, int n4) {
    int i = blockIdx.x * blockDim.x + threadIdx.x;
    if (i >= n4) return;
    float4 v = in[i];
    v4bf o;
    o[0] = (__bf16)v.x; o[1] = (__bf16)v.y; o[2] = (__bf16)v.z; o[3] = (__bf16)v.w;
    out[i] = o;
}

// ---------------- in-place RoPE on bf16 (B,S,nh*128), optional prescale -----
__global__ __launch_bounds__(256) void rope_inplace(
        __bf16* __restrict__ qk, const int* __restrict__ pos, int nh,
        int rowstride, float outscale) {
    int idx = blockIdx.x * blockDim.x + threadIdx.x;
    int d = idx & 63;
    int t = idx >> 6;
    int h = t % nh;
    int bs = t / nh;
    if (bs >= B_ * S_) return;
    int s = bs & (S_ - 1);
    float p = (float)pos[s];
    float inv = expf(-(float)d * (1.0f / 64.0f) * 13.122363377404329f);
    float ang = p * inv;
    float c = cosf(ang), sn = sinf(ang);
    size_t off = (size_t)bs * rowstride + (size_t)h * D_;
    float x1 = (float)qk[off + d];
    float x2 = (float)qk[off + d + 64];
    qk[off + d]      = (__bf16)((x1 * c - x2 * sn) * outscale);
    qk[off + d + 64] = (__bf16)((x2 * c + x1 * sn) * outscale);
}

// ---------------- GEMM 256x256/BK=64, 8 waves, m201-style 4-phase -----------
// C[M,N] = A[M,K] * B[N,K]^T, bf16 in, fp32 acc.
// Half-tiles defined by QUADRANT (not contiguity):
//   Ah(mh) = rows {wr*128 + mh*64 .. +64} for wr=0,1  (128 rows)
//   Bh(nh) = cols {wc*64 + nh*32 .. +32} for wc=0..3  (128 cols)
// LDS H[2][4][128*64], hid order 0=Ah0 1=Bh0 2=Bh1 3=Ah1 (= first-need order).
// Phase p of tile t: {ds_read new frags; stage HT p of t+1 into buf[t+1&1];
// barrier; lgkmcnt(0); setprio1; 16 MFMA; setprio0; [vmcnt(4)]; barrier}.
// vmcnt ledger (per-wave, made collective by the following barrier):
//   prologue 8 loads -> vmcnt(4) leaves {HT2,HT3}(t0) in flight.
//   ph0 close vmcnt(4) drains Bh1(t); ph1 close vmcnt(4) drains Ah1(t);
//   ph3 close vmcnt(4) drains Ah0/Bh0(t+1). Never 0 mid-loop; every HT has
//   >=3 phases of flight. Staging targets buf[t+1&1]; each region staged in
//   tile t phase p was last read in tile t-1 phase p (>=4 barriers) -> no WAR.
template <int EPI>
__global__ __launch_bounds__(512, 2) void gemm_bt(
        const __bf16* __restrict__ A, const __bf16* __restrict__ Bm,
        void* __restrict__ Cv, void* __restrict__ Cv2, int M, int N, int K) {
    __shared__ __bf16 H[2][4][128 * 64];
    const int tid  = threadIdx.x;
    const int wave = tid >> 6;
    const int lane = tid & 63;
    const int l15  = lane & 15;
    const int quad = lane >> 4;

    // XCD-chunked block swizzle (nwg % 8 == 0 for all our launches)
    const int nbx = N >> 8;
    const int nwg = (int)gridDim.x;
    const int swz = ((int)blockIdx.x & 7) * (nwg >> 3) + ((int)blockIdx.x >> 3);
    const int bm  = (swz / nbx) * 256;
    const int bn  = (swz % nbx) * 256;

    const int wr = wave >> 2;    // 0..1  (row group: 128 rows)
    const int wc = wave & 3;     // 0..3  (col group: 64 cols)

    v4f acc[8][4] = {};

    const int srow8 = tid >> 3;                 // 0..63
    const int scc   = (tid & 7) ^ (srow8 & 7);  // pre-swizzled source chunk

    // stage half-tile h of K-tile t (2 gloads; 16KB; dest linear, src swz)
    auto stageHT = [&](int t, int h) {
        char* dbase = (char*)&H[t & 1][h][0] + (size_t)wave * 1024;
        const size_t kof = (size_t)t * 64 + scc * 8;
        if (h == 0 || h == 3) {
            const int mh = (h == 3);
#pragma unroll
            for (int g = 0; g < 2; ++g) {
                int row = bm + g * 128 + mh * 64 + srow8;
                load_lds16(A + (size_t)row * K + kof, dbase + g * 8192);
            }
        } else {
            const int nh = (h == 2);
#pragma unroll
            for (int g = 0; g < 2; ++g) {
                int sc  = g * 64 + srow8;
                int col = bn + (sc >> 5) * 64 + nh * 32 + (sc & 31);
                load_lds16(Bm + (size_t)col * K + kof, dbase + g * 8192);
            }
        }
    };

    // prologue: tile 0, staged in first-need order; drain Ah0,Bh0
    stageHT(0, 0); stageHT(0, 1); stageHT(0, 2); stageHT(0, 3);
    asm volatile("s_waitcnt vmcnt(4)" ::: "memory");
    __builtin_amdgcn_s_barrier();

    const int nt = K >> 6;
    for (int t = 0; t < nt; ++t) {
        const int cur = t & 1;
        const bool more = (t + 1 < nt);
        const __bf16* A0p = &H[cur][0][0];
        const __bf16* B0p = &H[cur][1][0];
        const __bf16* B1p = &H[cur][2][0];
        const __bf16* A1p = &H[cur][3][0];
        v8bf a[4][2], b0[2][2], b1[2][2];

        // ================= phase 0: quadrant (mh0, nh0) =================
#pragma unroll
        for (int i = 0; i < 4; ++i)
#pragma unroll
            for (int kk = 0; kk < 2; ++kk)
                a[i][kk] = *(const v8bf*)&A0p[(wr * 64 + i * 16 + l15) * 64 +
                                              (((kk * 4 + quad) ^ (l15 & 7)) * 8)];
#pragma unroll
        for (int j = 0; j < 2; ++j)
#pragma unroll
            for (int kk = 0; kk < 2; ++kk)
                b0[j][kk] = *(const v8bf*)&B0p[(wc * 32 + j * 16 + l15) * 64 +
                                               (((kk * 4 + quad) ^ (l15 & 7)) * 8)];
        if (more) stageHT(t + 1, 0);
        __builtin_amdgcn_s_barrier();
        asm volatile("s_waitcnt lgkmcnt(0)" ::: "memory");
        __builtin_amdgcn_s_setprio(1);
#pragma unroll
        for (int kk = 0; kk < 2; ++kk)
#pragma unroll
            for (int i = 0; i < 4; ++i)
#pragma unroll
                for (int j = 0; j < 2; ++j)
                    acc[i][j] = mfma16(a[i][kk], b0[j][kk], acc[i][j]);
        __builtin_amdgcn_s_setprio(0);
        if (more) asm volatile("s_waitcnt vmcnt(4)" ::: "memory");  // Bh1(t) ready
        else      asm volatile("s_waitcnt vmcnt(2)" ::: "memory");
        __builtin_amdgcn_s_barrier();

        // ================= phase 1: quadrant (mh0, nh1) =================
#pragma unroll
        for (int j = 0; j < 2; ++j)
#pragma unroll
            for (int kk = 0; kk < 2; ++kk)
                b1[j][kk] = *(const v8bf*)&B1p[(wc * 32 + j * 16 + l15) * 64 +
                                               (((kk * 4 + quad) ^ (l15 & 7)) * 8)];
        if (more) stageHT(t + 1, 1);
        __builtin_amdgcn_s_barrier();
        asm volatile("s_waitcnt lgkmcnt(0)" ::: "memory");
        __builtin_amdgcn_s_setprio(1);
#pragma unroll
        for (int kk = 0; kk < 2; ++kk)
#pragma unroll
            for (int i = 0; i < 4; ++i)
#pragma unroll
                for (int j = 0; j < 2; ++j)
                    acc[i][2 + j] = mfma16(a[i][kk], b1[j][kk], acc[i][2 + j]);
        __builtin_amdgcn_s_setprio(0);
        if (more) asm volatile("s_waitcnt vmcnt(4)" ::: "memory");  // Ah1(t) ready
        else      asm volatile("s_waitcnt vmcnt(0)" ::: "memory");
        __builtin_amdgcn_s_barrier();

        // ================= phase 2: quadrant (mh1, nh1) =================
#pragma unroll
        for (int i = 0; i < 4; ++i)
#pragma unroll
            for (int kk = 0; kk < 2; ++kk)
                a[i][kk] = *(const v8bf*)&A1p[(wr * 64 + i * 16 + l15) * 64 +
                                              (((kk * 4 + quad) ^ (l15 & 7)) * 8)];
        if (more) stageHT(t + 1, 2);
        __builtin_amdgcn_s_barrier();
        asm volatile("s_waitcnt lgkmcnt(0)" ::: "memory");
        __builtin_amdgcn_s_setprio(1);
#pragma unroll
        for (int kk = 0; kk < 2; ++kk)
#pragma unroll
            for (int i = 0; i < 4; ++i)
#pragma unroll
                for (int j = 0; j < 2; ++j)
                    acc[4 + i][2 + j] = mfma16(a[i][kk], b1[j][kk], acc[4 + i][2 + j]);
        __builtin_amdgcn_s_setprio(0);
        __builtin_amdgcn_s_barrier();

        // ================= phase 3: quadrant (mh1, nh0), pure-reg =======
        if (more) stageHT(t + 1, 3);
        __builtin_amdgcn_s_barrier();
        __builtin_amdgcn_s_setprio(1);
#pragma unroll
        for (int kk = 0; kk < 2; ++kk)
#pragma unroll
            for (int i = 0; i < 4; ++i)
#pragma unroll
                for (int j = 0; j < 2; ++j)
                    acc[4 + i][j] = mfma16(a[i][kk], b0[j][kk], acc[4 + i][j]);
        __builtin_amdgcn_s_setprio(0);
        if (more) asm volatile("s_waitcnt vmcnt(4)" ::: "memory");  // Ah0,Bh0(t+1)
        __builtin_amdgcn_s_barrier();
    }

    // epilogue: C/D layout col = lane&15, row = quad*4 + r (m89/m91 verified)
#pragma unroll
    for (int mi = 0; mi < 8; ++mi) {
#pragma unroll
        for (int nj = 0; nj < 4; ++nj) {
#pragma unroll
            for (int r = 0; r < 4; ++r) {
                int row = bm + wr * 128 + mi * 16 + quad * 4 + r;
                int col = bn + wc * 64 + nj * 16 + l15;
                float val = acc[mi][nj][r];
                if (EPI == 0) {
                    ((float*)Cv)[(size_t)row * N + col] = val;
                } else if (EPI == 1) {
                    ((__bf16*)Cv)[(size_t)row * N + col] = (__bf16)val;
                } else {
                    if (col < 1024) {
                        ((__bf16*)Cv)[(size_t)row * 1024 + col] = (__bf16)val;
                    } else {
                        int cc = col - 1024;
                        int b  = row >> 11, s = row & (S_ - 1);
                        int kv = cc >> 7,  d = cc & (D_ - 1);
                        ((__bf16*)Cv2)[((size_t)((b * KV_ + kv) * D_ + d)) * S_ + s] = (__bf16)val;
                    }
                }
            }
        }
    }
}

// ---------------- fused causal flash attention (swapped-QK softmax) ---------
// (verified round 5: swapped QK^T lane-local softmax, defer-max THR=8,
// counted vmcnt dbuf staging, XCD-partitioned decode, 0-conflict P swizzle)
__global__ __launch_bounds__(256, 2) void attn_fused(
        const __bf16* __restrict__ q, const __bf16* __restrict__ k,
        const __bf16* __restrict__ vt, __bf16* __restrict__ attn) {
    __shared__ __bf16 Ks[2][64 * 128];   // [key][d], chunk16 c at c^(key&15)
    __shared__ __bf16 Vs[2][128 * 64];   // [d][key], chunk16 c at c^(d&7)
    __shared__ __bf16 P[4][16 * 64];     // per-wave P, chunk8 c at c^(row&7)
    const int wave = threadIdx.x >> 6;
    const int lane = threadIdx.x & 63;

    const int wgid = blockIdx.x;
    const int xcd  = wgid & 7;
    const int slot = wgid >> 3;               // 0..255
    const int bh   = xcd * 8 + (slot >> 5);   // 8 bh per XCD
    const int qblk = 31 - (slot & 31);        // long blocks first
    const int b = bh >> 5;       // H=32
    const int h = bh & 31;
    const int kvh = h >> 2;      // rep = H/KV = 4
    const int q0 = qblk * 64 + wave * 16;
    const int l15  = lane & 15;
    const int quad = lane >> 4;

    const __bf16* qbase = q  + (size_t)(b * S_) * E_ + (size_t)h * D_;
    const __bf16* kbase = k  + (size_t)(b * S_) * (KV_ * D_) + (size_t)kvh * D_;
    const __bf16* vbase = vt + (size_t)((b * KV_ + kvh) * D_) * S_;
    __bf16* Pw = &P[wave][0];

    const int krow_l = lane >> 4;
    const int kcc    = lane & 15;
    const int vrow_l = lane >> 3;
    const int vcc    = lane & 7;

    auto stageK = [&](int t, int buf) {
#pragma unroll
        for (int i = 0; i < 4; ++i) {
            int g = wave * 4 + i;
            int row = g * 4 + krow_l;
            int scc = kcc ^ (row & 15);
            load_lds16(kbase + (size_t)(t * 64 + row) * (KV_ * D_) + scc * 8,
                       (char*)&Ks[buf][0] + (size_t)g * 1024);
        }
    };
    auto stageV = [&](int t, int buf) {
#pragma unroll
        for (int i = 0; i < 4; ++i) {
            int g = wave * 4 + i;
            int row = g * 8 + vrow_l;
            int scc = vcc ^ (row & 7);
            load_lds16(vbase + (size_t)row * S_ + t * 64 + scc * 8,
                       (char*)&Vs[buf][0] + (size_t)g * 1024);
        }
    };

    stageK(0, 0);
    stageV(0, 0);

    v8bf aq[4];
#pragma unroll
    for (int kc = 0; kc < 4; ++kc)
        aq[kc] = *(const v8bf*)(qbase + (size_t)(q0 + l15) * E_ + kc * 32 + quad * 8);

    v4f o[8] = {};
    float m_i = -INFINITY, l_i = 0.f;   // per-lane state for query q0 + l15

    const int ntiles = qblk + 1;        // block-uniform

    for (int t = 0; t < ntiles; ++t) {
        const int cur = t & 1;
        if (t + 1 < ntiles) {
            stageK(t + 1, cur ^ 1);
            stageV(t + 1, cur ^ 1);
            asm volatile("s_waitcnt vmcnt(8)" ::: "memory");
        } else {
            asm volatile("s_waitcnt vmcnt(0)" ::: "memory");
        }
        __builtin_amdgcn_s_barrier();
        __builtin_amdgcn_sched_barrier(0);

        const int n0 = t * 64;
        const __bf16* Ksc = &Ks[cur][0];
        const __bf16* Vsc = &Vs[cur][0];

        // ---- QK^T swapped: C[row = key quad*4+r (+16j)][col = query l15] ----
        v4f s[4] = {};
        __builtin_amdgcn_s_setprio(1);
#pragma unroll
        for (int kc = 0; kc < 4; ++kc) {
            v8bf kf[4];
#pragma unroll
            for (int j = 0; j < 4; ++j)
                kf[j] = *(const v8bf*)&Ksc[(j * 16 + l15) * 128 +
                                           (((kc * 4 + quad) ^ l15) * 8)];
#pragma unroll
            for (int j = 0; j < 4; ++j)
                s[j] = mfma16(kf[j], aq[kc], s[j]);   // A=K, B=Q
        }
        __builtin_amdgcn_s_setprio(0);

        // ---- (boundary-only) causal mask: key > query -> -inf ----
        float e[4][4];
        if (n0 + 63 > q0) {
#pragma unroll
            for (int j = 0; j < 4; ++j)
#pragma unroll
                for (int r = 0; r < 4; ++r) {
                    float v = s[j][r];
                    if (n0 + j * 16 + quad * 4 + r > q0 + l15) v = -INFINITY;
                    e[j][r] = v;
                }
        } else {
#pragma unroll
            for (int j = 0; j < 4; ++j)
#pragma unroll
                for (int r = 0; r < 4; ++r)
                    e[j][r] = s[j][r];
        }

        // ---- online softmax: row is lane-local (16 vals) + 2 shfl steps ----
        float mloc = e[0][0];
#pragma unroll
        for (int j = 0; j < 4; ++j)
#pragma unroll
            for (int r = 0; r < 4; ++r)
                mloc = fmaxf(mloc, e[j][r]);
        mloc = fmaxf(mloc, __shfl_xor(mloc, 16, 64));
        mloc = fmaxf(mloc, __shfl_xor(mloc, 32, 64));

        // T13 defer-max: only rescale when the max grew by more than THR=8
        if (!__all(mloc - m_i <= 8.0f)) {
            float mnew = fmaxf(m_i, mloc);
            float alpha = __expf(m_i - mnew);   // exp(-inf)=0 on first tile
            m_i = mnew;
            l_i *= alpha;
            float af[4];
#pragma unroll
            for (int r = 0; r < 4; ++r)
                af[r] = __shfl(alpha, quad * 4 + r, 16);
#pragma unroll
            for (int c = 0; c < 8; ++c)
#pragma unroll
                for (int r = 0; r < 4; ++r)
                    o[c][r] *= af[r];
        }

        float psum = 0.f;
#pragma unroll
        for (int j = 0; j < 4; ++j)
#pragma unroll
            for (int r = 0; r < 4; ++r) {
                e[j][r] = __expf(e[j][r] - m_i);
                psum += e[j][r];
            }
        psum += __shfl_xor(psum, 16, 64);
        psum += __shfl_xor(psum, 32, 64);
        l_i += psum;

        // ---- P write: row = l15 (query), cols 16j + 4*quad + r, packed b64,
        //      chunk-XOR swizzle (stored chunk = logical ^ (row&7)) ----
#pragma unroll
        for (int j = 0; j < 4; ++j) {
            v4bf pk;
#pragma unroll
            for (int r = 0; r < 4; ++r) pk[r] = (__bf16)e[j][r];
            int cl = j * 2 + (quad >> 1);
            *(v4bf*)&Pw[l15 * 64 + ((cl ^ (l15 & 7)) << 3) + ((quad & 1) << 2)] = pk;
        }

        // re-read as A-fragment: row l15, logical chunks quad / 4+quad
        v8bf ap0 = *(const v8bf*)&Pw[l15 * 64 + ((quad ^ (l15 & 7)) << 3)];
        v8bf ap1 = *(const v8bf*)&Pw[l15 * 64 + (((4 + quad) ^ (l15 & 7)) << 3)];

        // ---- PV: o[d-tile] += P * V^T, V from LDS ----
        __builtin_amdgcn_s_setprio(1);
#pragma unroll
        for (int c = 0; c < 8; ++c) {
            v8bf v0 = *(const v8bf*)&Vsc[(c * 16 + l15) * 64 +
                                         ((quad ^ (l15 & 7)) * 8)];
            v8bf v1 = *(const v8bf*)&Vsc[(c * 16 + l15) * 64 +
                                         (((4 + quad) ^ (l15 & 7)) * 8)];
            o[c] = mfma16(ap0, v0, o[c]);
            o[c] = mfma16(ap1, v1, o[c]);
        }
        __builtin_amdgcn_s_setprio(0);

        __builtin_amdgcn_sched_barrier(0);
        asm volatile("s_waitcnt lgkmcnt(0)" ::: "memory");
        __builtin_amdgcn_s_barrier();
        __builtin_amdgcn_sched_barrier(0);
    }

    float linv = 1.0f / l_i;     // for query q0 + l15
    float lr[4];
#pragma unroll
    for (int r = 0; r < 4; ++r)
        lr[r] = __shfl(linv, quad * 4 + r, 16);
    __bf16* obase = attn + (size_t)(b * S_) * E_ + (size_t)h * D_;
#pragma unroll
    for (int c = 0; c < 8; ++c)
#pragma unroll
        for (int r = 0; r < 4; ++r)
            obase[(size_t)(q0 + quad * 4 + r) * E_ + c * 16 + l15] =
                (__bf16)(o[c][r] * lr[r]);
}

extern "C" void kernel_launch(void* const* d_in, const int* in_sizes, int n_in,
                              void* d_out, int out_size, void* d_ws, size_t ws_size,
                              hipStream_t stream) {
    (void)in_sizes; (void)n_in; (void)out_size; (void)ws_size;
    const float* x  = (const float*)d_in[0];
    const float* wq = (const float*)d_in[1];
    const float* wk = (const float*)d_in[2];
    const float* wv = (const float*)d_in[3];
    const float* wo = (const float*)d_in[4];
    const int*   pos = (const int*)d_in[5];
    float* out = (float*)d_out;

    char* ws = (char*)d_ws;
    size_t off = 0;
    auto alloc = [&](size_t bytes) {
        char* p = ws + off;
        off += (bytes + 255) & ~(size_t)255;
        return p;
    };
    __bf16* xb   = (__bf16*)alloc((size_t)B_ * S_ * E_ * 2);
    __bf16* wqb  = (__bf16*)alloc((size_t)E_ * E_ * 2);
    __bf16* wkvb = (__bf16*)alloc((size_t)2 * KV_ * D_ * E_ * 2);  // [wk;wv] rows
    __bf16* wob  = (__bf16*)alloc((size_t)E_ * E_ * 2);
    __bf16* qb   = (__bf16*)alloc((size_t)B_ * S_ * E_ * 2);
    __bf16* kb   = (__bf16*)alloc((size_t)B_ * S_ * KV_ * D_ * 2);
    __bf16* vt   = (__bf16*)alloc((size_t)B_ * KV_ * D_ * S_ * 2);
    __bf16* at   = (__bf16*)alloc((size_t)B_ * S_ * E_ * 2);

    auto cast = [&](const float* in, __bf16* ob, size_t n) {
        int n4 = (int)(n / 4);
        cast_f32_to_bf16<<<(n4 + 255) / 256, 256, 0, stream>>>(
            (const float4*)in, (v4bf*)ob, n4);
    };
    cast(x,  xb,  (size_t)B_ * S_ * E_);
    cast(wq, wqb, (size_t)E_ * E_);
    cast(wk, wkvb, (size_t)KV_ * D_ * E_);
    cast(wv, wkvb + (size_t)KV_ * D_ * E_, (size_t)KV_ * D_ * E_);
    cast(wo, wob, (size_t)E_ * E_);

    const int M = B_ * S_;
    const int nwg_e = (E_ / 256) * (M / 256);            // 256
    const int nwg_kv = (2 * KV_ * D_ / 256) * (M / 256); // 128
    gemm_bt<1><<<dim3(nwg_e), 512, 0, stream>>>(
        xb, wqb, qb, nullptr, M, E_, E_);
    gemm_bt<2><<<dim3(nwg_kv), 512, 0, stream>>>(
        xb, wkvb, kb, vt, M, 2 * KV_ * D_, E_);

    // q gets RoPE + 1/sqrt(D) prescale (fp32 math); k gets RoPE only.
    rope_inplace<<<(B_ * S_ * H_ * 64 + 255) / 256, 256, 0, stream>>>(
        qb, pos, H_, E_, 0.08838834764831845f);
    rope_inplace<<<(B_ * S_ * KV_ * 64 + 255) / 256, 256, 0, stream>>>(
        kb, pos, KV_, KV_ * D_, 1.0f);

    attn_fused<<<dim3(B_ * H_ * (S_ / 64)), 256, 0, stream>>>(qb, kb, vt, at);

    gemm_bt<0><<<dim3(nwg_e), 512, 0, stream>>>(
        at, wob, out, nullptr, M, E_, E_);
}